// Round 1
// baseline (989.396 us; speedup 1.0000x reference)
//
#include <hip/hip_runtime.h>
#include <stdint.h>

#define NQ 10000
#define NC 2048
#define NW 157           // ceil(10000/64)
#define IOU_TH 0.5f

// -------- ws layout (bytes) --------
// scores : [0,       40000)
// rank   : [40000,   80000)
// boxes4 : [80000,  240000)   10000*4 f32 (xyxy, clipped+scaled)
// sx1    : [240000, 280000)   sorted SoA
// sy1    : [280000, 320000)
// sx2    : [320000, 360000)
// sy2    : [360000, 400000)
// sarea  : [400000, 440000)
// order  : [440000, 480000)   sorted index -> original index
// mask   : [480000, 480000+10000*157*8 = 13,040,000)

__global__ __launch_bounds__(256) void k_scores(const float* __restrict__ logits,
        float* __restrict__ out_scores, float* __restrict__ out_labels,
        float* __restrict__ ws_scores) {
    int wave = threadIdx.x >> 6;
    int lane = threadIdx.x & 63;
    int q = blockIdx.x * 4 + wave;
    if (q >= NQ) return;
    const float* row = logits + (size_t)q * NC;
    float4 v[8];
    float m = -3.4e38f;
    int am = 0;
    #pragma unroll
    for (int k = 0; k < 8; k++) {
        int idx = k * 256 + lane * 4;
        v[k] = *(const float4*)(row + idx);
        // strict > keeps first occurrence within this lane's ascending indices
        if (v[k].x > m) { m = v[k].x; am = idx; }
        if (v[k].y > m) { m = v[k].y; am = idx + 1; }
        if (v[k].z > m) { m = v[k].z; am = idx + 2; }
        if (v[k].w > m) { m = v[k].w; am = idx + 3; }
    }
    #pragma unroll
    for (int off = 32; off >= 1; off >>= 1) {
        float om = __shfl_xor(m, off);
        int   oa = __shfl_xor(am, off);
        if (om > m || (om == m && oa < am)) { m = om; am = oa; }
    }
    float s = 0.f;
    #pragma unroll
    for (int k = 0; k < 8; k++) {
        s += expf(v[k].x - m);
        s += expf(v[k].y - m);
        s += expf(v[k].z - m);
        s += expf(v[k].w - m);
    }
    #pragma unroll
    for (int off = 32; off >= 1; off >>= 1) s += __shfl_xor(s, off);
    if (lane == 0) {
        float sc = 1.0f / s;           // max prob = exp(0)/sum = 1/sum
        out_scores[q] = sc;
        out_labels[q] = (float)am;
        ws_scores[q]  = sc;
    }
}

__global__ __launch_bounds__(256) void k_cls(const float* __restrict__ cls,
                                             float* __restrict__ out) {
    float m = -3.4e38f; int am = 0x7fffffff;
    for (int idx = threadIdx.x; idx < NC; idx += 256) {
        float x = cls[idx];
        if (x > m) { m = x; am = idx; }    // per-thread indices ascending
    }
    int lane = threadIdx.x & 63, wave = threadIdx.x >> 6;
    #pragma unroll
    for (int off = 32; off >= 1; off >>= 1) {
        float om = __shfl_xor(m, off); int oa = __shfl_xor(am, off);
        if (om > m || (om == m && oa < am)) { m = om; am = oa; }
    }
    __shared__ float sm[4]; __shared__ int sa[4];
    if (lane == 0) { sm[wave] = m; sa[wave] = am; }
    __syncthreads();
    if (threadIdx.x == 0) {
        for (int w = 1; w < 4; w++)
            if (sm[w] > m || (sm[w] == m && sa[w] < am)) { m = sm[w]; am = sa[w]; }
        out[0] = (float)am;
    }
}

__global__ __launch_bounds__(256) void k_boxes(const float* __restrict__ pb,
        const int* __restrict__ ts, float* __restrict__ out_boxes,
        float* __restrict__ boxes4, int* __restrict__ rank) {
    #pragma clang fp contract(off)
    int i = blockIdx.x * 256 + threadIdx.x;
    if (i >= NQ) return;
    rank[i] = 0;
    // target_sizes may be int64 (low/high word pairs) or int32; values in [480,1333)
    int a0 = ts[0], a1 = ts[1];
    int ih, iw;
    if (a1 == 0) { ih = a0; iw = ts[2]; } else { ih = a0; iw = a1; }
    float sh = (float)ih, sw = (float)iw;
    float4 b = *(const float4*)(pb + i * 4);
    float x1 = b.x - 0.5f * b.z;
    float y1 = b.y - 0.5f * b.w;
    float x2 = b.x + 0.5f * b.z;
    float y2 = b.y + 0.5f * b.w;
    x1 = fminf(fmaxf(x1, 0.f), 1.f) * sw;
    y1 = fminf(fmaxf(y1, 0.f), 1.f) * sh;
    x2 = fminf(fmaxf(x2, 0.f), 1.f) * sw;
    y2 = fminf(fmaxf(y2, 0.f), 1.f) * sh;
    float4 o = make_float4(x1, y1, x2, y2);
    *(float4*)(out_boxes + i * 4) = o;
    *(float4*)(boxes4 + i * 4) = o;
}

// rank[i] = #{j: s_j > s_i} + #{j: s_j == s_i && j < i}  == position in argsort(-s) (stable)
__global__ __launch_bounds__(256) void k_count(const float* __restrict__ scores,
                                               int* __restrict__ rank) {
    __shared__ float sc[2000];
    int jbase = blockIdx.y * 2000;
    int jn = min(2000, NQ - jbase);
    for (int t = threadIdx.x; t < jn; t += 256) sc[t] = scores[jbase + t];
    __syncthreads();
    int i = blockIdx.x * 256 + threadIdx.x;
    if (i >= NQ) return;
    float si = scores[i];
    int cnt = 0;
    for (int jj = 0; jj < jn; jj++) {
        float sj = sc[jj];
        int j = jbase + jj;
        cnt += (sj > si) || (sj == si && j < i);
    }
    if (cnt) atomicAdd(&rank[i], cnt);
}

__global__ __launch_bounds__(256) void k_scatter(const float* __restrict__ boxes4,
        const int* __restrict__ rank, int* __restrict__ order,
        float* __restrict__ sx1, float* __restrict__ sy1,
        float* __restrict__ sx2, float* __restrict__ sy2,
        float* __restrict__ sarea) {
    #pragma clang fp contract(off)
    int i = blockIdx.x * 256 + threadIdx.x;
    if (i >= NQ) return;
    int r = rank[i];
    order[r] = i;
    float4 b = *(const float4*)(boxes4 + i * 4);
    sx1[r] = b.x; sy1[r] = b.y; sx2[r] = b.z; sy2[r] = b.w;
    sarea[r] = fmaxf(b.z - b.x, 0.f) * fmaxf(b.w - b.y, 0.f);
}

// mask[i][cb] bit jj = (j>i) && IoU(i, j)>0.5, j = cb*64+jj (sorted order)
__global__ __launch_bounds__(64) void k_mask(const float* __restrict__ sx1,
        const float* __restrict__ sy1, const float* __restrict__ sx2,
        const float* __restrict__ sy2, const float* __restrict__ sarea,
        unsigned long long* __restrict__ mask) {
    #pragma clang fp contract(off)
    int rb = blockIdx.x, cb = blockIdx.y;
    if (cb < rb) return;
    int t = threadIdx.x;
    __shared__ float cx1[64], cy1[64], cx2[64], cy2[64], ca[64];
    int j0 = cb * 64 + t;
    if (j0 < NQ) { cx1[t]=sx1[j0]; cy1[t]=sy1[j0]; cx2[t]=sx2[j0]; cy2[t]=sy2[j0]; ca[t]=sarea[j0]; }
    __syncthreads();
    int i = rb * 64 + t;
    if (i >= NQ) return;
    float xi1 = sx1[i], yi1 = sy1[i], xi2 = sx2[i], yi2 = sy2[i], ai = sarea[i];
    int ncol = min(64, NQ - cb * 64);
    unsigned long long word = 0;
    for (int jj = 0; jj < ncol; jj++) {
        int j = cb * 64 + jj;
        float lx = fmaxf(xi1, cx1[jj]);
        float ly = fmaxf(yi1, cy1[jj]);
        float rx = fminf(xi2, cx2[jj]);
        float ry = fminf(yi2, cy2[jj]);
        float w = fmaxf(rx - lx, 0.f);
        float h = fmaxf(ry - ly, 0.f);
        float inter = w * h;
        float denom = (ai + ca[jj]) - inter;   // ref op order: (areas[i]+areas)-inter
        float iou = inter / denom;
        bool sup = (iou > IOU_TH) && (j > i);
        word |= ((unsigned long long)(sup ? 1u : 0u)) << jj;
    }
    mask[(size_t)i * NW + cb] = word;
}

// single-block sequential greedy reduce; wave0 decides, all 4 waves OR kept rows
__global__ __launch_bounds__(256) void k_scan(const unsigned long long* __restrict__ mask,
        const int* __restrict__ order, float* __restrict__ out_keep) {
    __shared__ unsigned long long removed[NW];
    __shared__ unsigned long long lds_km;
    int tid = threadIdx.x;
    int wave = tid >> 6, lane = tid & 63;
    for (int w = tid; w < NW; w += 256) removed[w] = 0ull;
    __syncthreads();
    for (int c = 0; c < NW; c++) {
        if (wave == 0) {
            int i = c * 64 + lane;
            unsigned long long diag = (i < NQ) ? mask[(size_t)i * NW + c] : 0ull;
            int o = (i < NQ) ? order[i] : 0;
            unsigned long long cur = removed[c];       // uniform broadcast read
            int nvalid = min(64, NQ - c * 64);
            if (nvalid < 64) cur |= (~0ull) << nvalid; // invalid bits = suppressed
            for (int b = 0; b < 64; b++) {
                unsigned long long d = __shfl(diag, b);
                // if bit b alive, OR row b's diag word (only sets bits > b)
                cur |= (((cur >> b) & 1ull) - 1ull) & d;
            }
            if (i < NQ) out_keep[o] = ((cur >> lane) & 1ull) ? 0.f : 1.f;
            if (lane == 0) lds_km = ~cur;              // kept bits in this chunk
        }
        __syncthreads();
        unsigned long long km = lds_km;
        int r = 0;
        while (km) {
            int b = __ffsll(km) - 1;
            km &= km - 1;
            if ((r & 3) == wave) {
                const unsigned long long* rowp = mask + (size_t)(c * 64 + b) * NW;
                for (int j = c + 1 + lane; j < NW; j += 64)
                    atomicOr(&removed[j], rowp[j]);
            }
            r++;
        }
        __syncthreads();
    }
}

extern "C" void kernel_launch(void* const* d_in, const int* in_sizes, int n_in,
                              void* d_out, int out_size, void* d_ws, size_t ws_size,
                              hipStream_t stream) {
    const float* pred_logits = (const float*)d_in[0];
    const float* pred_boxes  = (const float*)d_in[1];
    const float* cls_logits  = (const float*)d_in[2];
    const int*   tsizes      = (const int*)d_in[3];

    float* out = (float*)d_out;
    float* out_scores = out;
    float* out_labels = out + 10000;
    float* out_boxes  = out + 20000;
    float* out_keep   = out + 60000;
    float* out_cls    = out + 70000;

    char* ws = (char*)d_ws;
    float* ws_scores = (float*)(ws + 0);
    int*   rank      = (int*)  (ws + 40000);
    float* boxes4    = (float*)(ws + 80000);
    float* sx1       = (float*)(ws + 240000);
    float* sy1       = (float*)(ws + 280000);
    float* sx2       = (float*)(ws + 320000);
    float* sy2       = (float*)(ws + 360000);
    float* sarea     = (float*)(ws + 400000);
    int*   order     = (int*)  (ws + 440000);
    unsigned long long* mask = (unsigned long long*)(ws + 480000);

    k_scores<<<2500, 256, 0, stream>>>(pred_logits, out_scores, out_labels, ws_scores);
    k_cls<<<1, 256, 0, stream>>>(cls_logits, out_cls);
    k_boxes<<<40, 256, 0, stream>>>(pred_boxes, tsizes, out_boxes, boxes4, rank);
    k_count<<<dim3(40, 5), 256, 0, stream>>>(ws_scores, rank);
    k_scatter<<<40, 256, 0, stream>>>(boxes4, rank, order, sx1, sy1, sx2, sy2, sarea);
    k_mask<<<dim3(157, 157), 64, 0, stream>>>(sx1, sy1, sx2, sy2, sarea, mask);
    k_scan<<<1, 256, 0, stream>>>(mask, order, out_keep);
}

// Round 2
// 975.083 us; speedup vs baseline: 1.0147x; 1.0147x over previous
//
#include <hip/hip_runtime.h>
#include <stdint.h>

#define NQ 10000
#define NC 2048
#define NW 157           // ceil(10000/64)
#define IOU_TH 0.5f

// -------- ws layout (bytes) --------
// scores : [0,       40000)
// rank   : [40000,   80000)
// boxes4 : [80000,  240000)   10000*4 f32 (xyxy, clipped+scaled)
// sx1    : [240000, 280000)   sorted SoA
// sy1    : [280000, 320000)
// sx2    : [320000, 360000)
// sy2    : [360000, 400000)
// sarea  : [400000, 440000)
// order  : [440000, 480000)   sorted index -> original index
// mask   : [480000, 480000+10000*157*8 = 13,040,000)

__global__ __launch_bounds__(256) void k_scores(const float* __restrict__ logits,
        float* __restrict__ out_scores, float* __restrict__ out_labels,
        float* __restrict__ ws_scores) {
    int wave = threadIdx.x >> 6;
    int lane = threadIdx.x & 63;
    int q = blockIdx.x * 4 + wave;
    if (q >= NQ) return;
    const float* row = logits + (size_t)q * NC;
    float4 v[8];
    float m = -3.4e38f;
    int am = 0;
    #pragma unroll
    for (int k = 0; k < 8; k++) {
        int idx = k * 256 + lane * 4;
        v[k] = *(const float4*)(row + idx);
        // strict > keeps first occurrence within this lane's ascending indices
        if (v[k].x > m) { m = v[k].x; am = idx; }
        if (v[k].y > m) { m = v[k].y; am = idx + 1; }
        if (v[k].z > m) { m = v[k].z; am = idx + 2; }
        if (v[k].w > m) { m = v[k].w; am = idx + 3; }
    }
    #pragma unroll
    for (int off = 32; off >= 1; off >>= 1) {
        float om = __shfl_xor(m, off);
        int   oa = __shfl_xor(am, off);
        if (om > m || (om == m && oa < am)) { m = om; am = oa; }
    }
    float s = 0.f;
    #pragma unroll
    for (int k = 0; k < 8; k++) {
        s += expf(v[k].x - m);
        s += expf(v[k].y - m);
        s += expf(v[k].z - m);
        s += expf(v[k].w - m);
    }
    #pragma unroll
    for (int off = 32; off >= 1; off >>= 1) s += __shfl_xor(s, off);
    if (lane == 0) {
        float sc = 1.0f / s;           // max prob = exp(0)/sum = 1/sum
        out_scores[q] = sc;
        out_labels[q] = (float)am;
        ws_scores[q]  = sc;
    }
}

__global__ __launch_bounds__(256) void k_cls(const float* __restrict__ cls,
                                             float* __restrict__ out) {
    float m = -3.4e38f; int am = 0x7fffffff;
    for (int idx = threadIdx.x; idx < NC; idx += 256) {
        float x = cls[idx];
        if (x > m) { m = x; am = idx; }    // per-thread indices ascending
    }
    int lane = threadIdx.x & 63, wave = threadIdx.x >> 6;
    #pragma unroll
    for (int off = 32; off >= 1; off >>= 1) {
        float om = __shfl_xor(m, off); int oa = __shfl_xor(am, off);
        if (om > m || (om == m && oa < am)) { m = om; am = oa; }
    }
    __shared__ float sm[4]; __shared__ int sa[4];
    if (lane == 0) { sm[wave] = m; sa[wave] = am; }
    __syncthreads();
    if (threadIdx.x == 0) {
        for (int w = 1; w < 4; w++)
            if (sm[w] > m || (sm[w] == m && sa[w] < am)) { m = sm[w]; am = sa[w]; }
        out[0] = (float)am;
    }
}

__global__ __launch_bounds__(256) void k_boxes(const float* __restrict__ pb,
        const int* __restrict__ ts, float* __restrict__ out_boxes,
        float* __restrict__ boxes4, int* __restrict__ rank) {
    #pragma clang fp contract(off)
    int i = blockIdx.x * 256 + threadIdx.x;
    if (i >= NQ) return;
    rank[i] = 0;
    // target_sizes may be int64 (low/high word pairs) or int32; values in [480,1333)
    int a0 = ts[0], a1 = ts[1];
    int ih, iw;
    if (a1 == 0) { ih = a0; iw = ts[2]; } else { ih = a0; iw = a1; }
    float sh = (float)ih, sw = (float)iw;
    float4 b = *(const float4*)(pb + i * 4);
    float x1 = b.x - 0.5f * b.z;
    float y1 = b.y - 0.5f * b.w;
    float x2 = b.x + 0.5f * b.z;
    float y2 = b.y + 0.5f * b.w;
    x1 = fminf(fmaxf(x1, 0.f), 1.f) * sw;
    y1 = fminf(fmaxf(y1, 0.f), 1.f) * sh;
    x2 = fminf(fmaxf(x2, 0.f), 1.f) * sw;
    y2 = fminf(fmaxf(y2, 0.f), 1.f) * sh;
    float4 o = make_float4(x1, y1, x2, y2);
    *(float4*)(out_boxes + i * 4) = o;
    *(float4*)(boxes4 + i * 4) = o;
}

// rank[i] = #{j: s_j > s_i} + #{j: s_j == s_i && j < i}  == position in argsort(-s) (stable)
__global__ __launch_bounds__(256) void k_count(const float* __restrict__ scores,
                                               int* __restrict__ rank) {
    __shared__ float sc[2000];
    int jbase = blockIdx.y * 2000;
    int jn = min(2000, NQ - jbase);
    for (int t = threadIdx.x; t < jn; t += 256) sc[t] = scores[jbase + t];
    __syncthreads();
    int i = blockIdx.x * 256 + threadIdx.x;
    if (i >= NQ) return;
    float si = scores[i];
    int cnt = 0;
    for (int jj = 0; jj < jn; jj++) {
        float sj = sc[jj];
        int j = jbase + jj;
        cnt += (sj > si) || (sj == si && j < i);
    }
    if (cnt) atomicAdd(&rank[i], cnt);
}

__global__ __launch_bounds__(256) void k_scatter(const float* __restrict__ boxes4,
        const int* __restrict__ rank, int* __restrict__ order,
        float* __restrict__ sx1, float* __restrict__ sy1,
        float* __restrict__ sx2, float* __restrict__ sy2,
        float* __restrict__ sarea) {
    #pragma clang fp contract(off)
    int i = blockIdx.x * 256 + threadIdx.x;
    if (i >= NQ) return;
    int r = rank[i];
    order[r] = i;
    float4 b = *(const float4*)(boxes4 + i * 4);
    sx1[r] = b.x; sy1[r] = b.y; sx2[r] = b.z; sy2[r] = b.w;
    sarea[r] = fmaxf(b.z - b.x, 0.f) * fmaxf(b.w - b.y, 0.f);
}

// mask[i][cb] bit jj = (j>i) && IoU(i, j)>0.5, j = cb*64+jj (sorted order)
__global__ __launch_bounds__(64) void k_mask(const float* __restrict__ sx1,
        const float* __restrict__ sy1, const float* __restrict__ sx2,
        const float* __restrict__ sy2, const float* __restrict__ sarea,
        unsigned long long* __restrict__ mask) {
    #pragma clang fp contract(off)
    int rb = blockIdx.x, cb = blockIdx.y;
    if (cb < rb) return;
    int t = threadIdx.x;
    __shared__ float cx1[64], cy1[64], cx2[64], cy2[64], ca[64];
    int j0 = cb * 64 + t;
    if (j0 < NQ) { cx1[t]=sx1[j0]; cy1[t]=sy1[j0]; cx2[t]=sx2[j0]; cy2[t]=sy2[j0]; ca[t]=sarea[j0]; }
    __syncthreads();
    int i = rb * 64 + t;
    if (i >= NQ) return;
    float xi1 = sx1[i], yi1 = sy1[i], xi2 = sx2[i], yi2 = sy2[i], ai = sarea[i];
    int ncol = min(64, NQ - cb * 64);
    unsigned long long word = 0;
    for (int jj = 0; jj < ncol; jj++) {
        int j = cb * 64 + jj;
        float lx = fmaxf(xi1, cx1[jj]);
        float ly = fmaxf(yi1, cy1[jj]);
        float rx = fminf(xi2, cx2[jj]);
        float ry = fminf(yi2, cy2[jj]);
        float w = fmaxf(rx - lx, 0.f);
        float h = fmaxf(ry - ly, 0.f);
        float inter = w * h;
        float denom = (ai + ca[jj]) - inter;   // ref op order: (areas[i]+areas)-inter
        float iou = inter / denom;
        bool sup = (iou > IOU_TH) && (j > i);
        word |= ((unsigned long long)(sup ? 1u : 0u)) << jj;
    }
    mask[(size_t)i * NW + cb] = word;
}

// Single-wave sequential greedy reduce. The 157-word "removed" bitmap lives in
// VGPRs: word w on lane (w & 63), register (w >> 6). No LDS, no barriers.
// Per chunk: skip-based resolve over alive bits (uniform __shfl = v_readlane),
// then batched row-OR loads (groups of 4 kept rows -> 12 independent loads).
__global__ __launch_bounds__(64) void k_scan(const unsigned long long* __restrict__ mask,
        const int* __restrict__ order, float* __restrict__ out_keep) {
    int lane = threadIdx.x & 63;
    unsigned long long r0 = 0, r1 = 0, r2 = 0;   // removed words lane, lane+64, lane+128
    const int w0 = lane, w1 = lane + 64, w2 = lane + 128;
    const bool w2v = (w2 < NW);

    // prefetch chunk 0's diag word + order
    unsigned long long dg = mask[(size_t)lane * NW + 0];
    int ord = order[lane];

    for (int c = 0; c < NW; c++) {
        // ---- prefetch next chunk (k_mask outputs, never mutated) ----
        unsigned long long dg_n = 0; int ord_n = 0;
        if (c + 1 < NW) {
            int i2 = (c + 1) * 64 + lane;
            if (i2 < NQ) {
                dg_n  = mask[(size_t)i2 * NW + (c + 1)];
                ord_n = order[i2];
            }
        }

        // ---- removed-in word for this chunk ----
        unsigned long long rsel = (c < 64) ? r0 : (c < 128) ? r1 : r2;
        unsigned long long cur = __shfl(rsel, c & 63);
        int nvalid = min(64, NQ - c * 64);
        if (nvalid < 64) cur |= (~0ull) << nvalid;   // invalid tail = suppressed

        // ---- skip-based greedy resolve (wave-uniform scalar chain) ----
        unsigned long long alive = ~cur;
        unsigned long long kept = 0;
        while (alive) {
            int b = (int)__builtin_ctzll(alive);
            unsigned long long d = __shfl(dg, b);    // row b's diag word (bits > b only)
            kept |= 1ull << b;
            cur  |= d;
            alive &= ~(d | (1ull << b));
        }

        // ---- write keep for this chunk ----
        int i = c * 64 + lane;
        if (i < NQ) out_keep[ord] = ((cur >> lane) & 1ull) ? 0.f : 1.f;

        // ---- OR kept rows' suffix words into the register bitmap ----
        // groups of 4 rows: 12 independent loads in flight before the ORs
        unsigned long long kmr = kept;
        while (kmr) {
            int bs[4];
            #pragma unroll
            for (int t = 0; t < 4; t++) {
                bs[t] = -1;
                if (kmr) { bs[t] = (int)__builtin_ctzll(kmr); kmr &= kmr - 1; }
            }
            unsigned long long a0 = 0, a1 = 0, a2 = 0;
            #pragma unroll
            for (int t = 0; t < 4; t++) {
                if (bs[t] >= 0) {
                    const unsigned long long* rowp = mask + (size_t)(c * 64 + bs[t]) * NW;
                    unsigned long long x0 = (w0 > c)        ? rowp[w0] : 0ull;
                    unsigned long long x1 = (w1 > c)        ? rowp[w1] : 0ull;
                    unsigned long long x2 = (w2v && w2 > c) ? rowp[w2] : 0ull;
                    a0 |= x0; a1 |= x1; a2 |= x2;
                }
            }
            r0 |= a0; r1 |= a1; r2 |= a2;
        }

        dg = dg_n; ord = ord_n;
    }
}

extern "C" void kernel_launch(void* const* d_in, const int* in_sizes, int n_in,
                              void* d_out, int out_size, void* d_ws, size_t ws_size,
                              hipStream_t stream) {
    const float* pred_logits = (const float*)d_in[0];
    const float* pred_boxes  = (const float*)d_in[1];
    const float* cls_logits  = (const float*)d_in[2];
    const int*   tsizes      = (const int*)d_in[3];

    float* out = (float*)d_out;
    float* out_scores = out;
    float* out_labels = out + 10000;
    float* out_boxes  = out + 20000;
    float* out_keep   = out + 60000;
    float* out_cls    = out + 70000;

    char* ws = (char*)d_ws;
    float* ws_scores = (float*)(ws + 0);
    int*   rank      = (int*)  (ws + 40000);
    float* boxes4    = (float*)(ws + 80000);
    float* sx1       = (float*)(ws + 240000);
    float* sy1       = (float*)(ws + 280000);
    float* sx2       = (float*)(ws + 320000);
    float* sy2       = (float*)(ws + 360000);
    float* sarea     = (float*)(ws + 400000);
    int*   order     = (int*)  (ws + 440000);
    unsigned long long* mask = (unsigned long long*)(ws + 480000);

    k_scores<<<2500, 256, 0, stream>>>(pred_logits, out_scores, out_labels, ws_scores);
    k_cls<<<1, 256, 0, stream>>>(cls_logits, out_cls);
    k_boxes<<<40, 256, 0, stream>>>(pred_boxes, tsizes, out_boxes, boxes4, rank);
    k_count<<<dim3(40, 5), 256, 0, stream>>>(ws_scores, rank);
    k_scatter<<<40, 256, 0, stream>>>(boxes4, rank, order, sx1, sy1, sx2, sy2, sarea);
    k_mask<<<dim3(157, 157), 64, 0, stream>>>(sx1, sy1, sx2, sy2, sarea, mask);
    k_scan<<<1, 64, 0, stream>>>(mask, order, out_keep);
}

// Round 3
// 577.124 us; speedup vs baseline: 1.7144x; 1.6896x over previous
//
#include <hip/hip_runtime.h>
#include <stdint.h>

#define NQ 10000
#define NC 2048
#define NW 157           // ceil(10000/64)
#define IOU_TH 0.5f

// -------- ws layout (bytes) --------
// scores : [0,       40000)
// rank   : [40000,   80000)
// boxes4 : [80000,  240000)   10000*4 f32 (xyxy, clipped+scaled)
// sx1    : [240000, 280000)   sorted SoA
// sy1    : [280000, 320000)
// sx2    : [320000, 360000)
// sy2    : [360000, 400000)
// sarea  : [400000, 440000)
// order  : [440000, 480000)   sorted index -> original index
// mask   : [480000, 480000+10000*157*8 = 13,040,000)

__global__ __launch_bounds__(256) void k_scores(const float* __restrict__ logits,
        float* __restrict__ out_scores, float* __restrict__ out_labels,
        float* __restrict__ ws_scores) {
    int wave = threadIdx.x >> 6;
    int lane = threadIdx.x & 63;
    int q = blockIdx.x * 4 + wave;
    if (q >= NQ) return;
    const float* row = logits + (size_t)q * NC;
    float4 v[8];
    float m = -3.4e38f;
    int am = 0;
    #pragma unroll
    for (int k = 0; k < 8; k++) {
        int idx = k * 256 + lane * 4;
        v[k] = *(const float4*)(row + idx);
        // strict > keeps first occurrence within this lane's ascending indices
        if (v[k].x > m) { m = v[k].x; am = idx; }
        if (v[k].y > m) { m = v[k].y; am = idx + 1; }
        if (v[k].z > m) { m = v[k].z; am = idx + 2; }
        if (v[k].w > m) { m = v[k].w; am = idx + 3; }
    }
    #pragma unroll
    for (int off = 32; off >= 1; off >>= 1) {
        float om = __shfl_xor(m, off);
        int   oa = __shfl_xor(am, off);
        if (om > m || (om == m && oa < am)) { m = om; am = oa; }
    }
    float s = 0.f;
    #pragma unroll
    for (int k = 0; k < 8; k++) {
        s += expf(v[k].x - m);
        s += expf(v[k].y - m);
        s += expf(v[k].z - m);
        s += expf(v[k].w - m);
    }
    #pragma unroll
    for (int off = 32; off >= 1; off >>= 1) s += __shfl_xor(s, off);
    if (lane == 0) {
        float sc = 1.0f / s;           // max prob = exp(0)/sum = 1/sum
        out_scores[q] = sc;
        out_labels[q] = (float)am;
        ws_scores[q]  = sc;
    }
}

__global__ __launch_bounds__(256) void k_cls(const float* __restrict__ cls,
                                             float* __restrict__ out) {
    float m = -3.4e38f; int am = 0x7fffffff;
    for (int idx = threadIdx.x; idx < NC; idx += 256) {
        float x = cls[idx];
        if (x > m) { m = x; am = idx; }    // per-thread indices ascending
    }
    int lane = threadIdx.x & 63, wave = threadIdx.x >> 6;
    #pragma unroll
    for (int off = 32; off >= 1; off >>= 1) {
        float om = __shfl_xor(m, off); int oa = __shfl_xor(am, off);
        if (om > m || (om == m && oa < am)) { m = om; am = oa; }
    }
    __shared__ float sm[4]; __shared__ int sa[4];
    if (lane == 0) { sm[wave] = m; sa[wave] = am; }
    __syncthreads();
    if (threadIdx.x == 0) {
        for (int w = 1; w < 4; w++)
            if (sm[w] > m || (sm[w] == m && sa[w] < am)) { m = sm[w]; am = sa[w]; }
        out[0] = (float)am;
    }
}

__global__ __launch_bounds__(256) void k_boxes(const float* __restrict__ pb,
        const int* __restrict__ ts, float* __restrict__ out_boxes,
        float* __restrict__ boxes4, int* __restrict__ rank) {
    #pragma clang fp contract(off)
    int i = blockIdx.x * 256 + threadIdx.x;
    if (i >= NQ) return;
    rank[i] = 0;
    // target_sizes may be int64 (low/high word pairs) or int32; values in [480,1333)
    int a0 = ts[0], a1 = ts[1];
    int ih, iw;
    if (a1 == 0) { ih = a0; iw = ts[2]; } else { ih = a0; iw = a1; }
    float sh = (float)ih, sw = (float)iw;
    float4 b = *(const float4*)(pb + i * 4);
    float x1 = b.x - 0.5f * b.z;
    float y1 = b.y - 0.5f * b.w;
    float x2 = b.x + 0.5f * b.z;
    float y2 = b.y + 0.5f * b.w;
    x1 = fminf(fmaxf(x1, 0.f), 1.f) * sw;
    y1 = fminf(fmaxf(y1, 0.f), 1.f) * sh;
    x2 = fminf(fmaxf(x2, 0.f), 1.f) * sw;
    y2 = fminf(fmaxf(y2, 0.f), 1.f) * sh;
    float4 o = make_float4(x1, y1, x2, y2);
    *(float4*)(out_boxes + i * 4) = o;
    *(float4*)(boxes4 + i * 4) = o;
}

// rank[i] = #{j: s_j > s_i} + #{j: s_j == s_i && j < i}  == position in argsort(-s) (stable)
__global__ __launch_bounds__(256) void k_count(const float* __restrict__ scores,
                                               int* __restrict__ rank) {
    __shared__ float sc[2000];
    int jbase = blockIdx.y * 2000;
    int jn = min(2000, NQ - jbase);
    for (int t = threadIdx.x; t < jn; t += 256) sc[t] = scores[jbase + t];
    __syncthreads();
    int i = blockIdx.x * 256 + threadIdx.x;
    if (i >= NQ) return;
    float si = scores[i];
    int cnt = 0;
    for (int jj = 0; jj < jn; jj++) {
        float sj = sc[jj];
        int j = jbase + jj;
        cnt += (sj > si) || (sj == si && j < i);
    }
    if (cnt) atomicAdd(&rank[i], cnt);
}

__global__ __launch_bounds__(256) void k_scatter(const float* __restrict__ boxes4,
        const int* __restrict__ rank, int* __restrict__ order,
        float* __restrict__ sx1, float* __restrict__ sy1,
        float* __restrict__ sx2, float* __restrict__ sy2,
        float* __restrict__ sarea) {
    #pragma clang fp contract(off)
    int i = blockIdx.x * 256 + threadIdx.x;
    if (i >= NQ) return;
    int r = rank[i];
    order[r] = i;
    float4 b = *(const float4*)(boxes4 + i * 4);
    sx1[r] = b.x; sy1[r] = b.y; sx2[r] = b.z; sy2[r] = b.w;
    sarea[r] = fmaxf(b.z - b.x, 0.f) * fmaxf(b.w - b.y, 0.f);
}

// mask[i][cb] bit jj = (j>i) && IoU(i, j)>0.5, j = cb*64+jj (sorted order)
__global__ __launch_bounds__(64) void k_mask(const float* __restrict__ sx1,
        const float* __restrict__ sy1, const float* __restrict__ sx2,
        const float* __restrict__ sy2, const float* __restrict__ sarea,
        unsigned long long* __restrict__ mask) {
    #pragma clang fp contract(off)
    int rb = blockIdx.x, cb = blockIdx.y;
    if (cb < rb) return;
    int t = threadIdx.x;
    __shared__ float cx1[64], cy1[64], cx2[64], cy2[64], ca[64];
    int j0 = cb * 64 + t;
    if (j0 < NQ) { cx1[t]=sx1[j0]; cy1[t]=sy1[j0]; cx2[t]=sx2[j0]; cy2[t]=sy2[j0]; ca[t]=sarea[j0]; }
    __syncthreads();
    int i = rb * 64 + t;
    if (i >= NQ) return;
    float xi1 = sx1[i], yi1 = sy1[i], xi2 = sx2[i], yi2 = sy2[i], ai = sarea[i];
    int ncol = min(64, NQ - cb * 64);
    unsigned long long word = 0;
    for (int jj = 0; jj < ncol; jj++) {
        int j = cb * 64 + jj;
        float lx = fmaxf(xi1, cx1[jj]);
        float ly = fmaxf(yi1, cy1[jj]);
        float rx = fminf(xi2, cx2[jj]);
        float ry = fminf(yi2, cy2[jj]);
        float w = fmaxf(rx - lx, 0.f);
        float h = fmaxf(ry - ly, 0.f);
        float inter = w * h;
        float denom = (ai + ca[jj]) - inter;   // ref op order: (areas[i]+areas)-inter
        float iou = inter / denom;
        bool sup = (iou > IOU_TH) && (j > i);
        word |= ((unsigned long long)(sup ? 1u : 0u)) << jj;
    }
    mask[(size_t)i * NW + cb] = word;
}

// Single-wave sequential greedy reduce.
// - "removed" bitmap in VGPRs: word w held by lane (w & 63), slot (w >> 6).
// - Resolve loop is fully SCALAR: alive/cur/kept live in SGPRs; row words are
//   fetched with v_readlane (SGPR lane index) -> ~15 cyc/step, not ds_bpermute.
// - Row-suffix ORs: two 8-row buffers issued back-to-back (48 loads in flight)
//   before the first consuming OR -> ~2 latency exposures per chunk, not ~8.
__global__ __launch_bounds__(64) void k_scan(const unsigned long long* __restrict__ mask,
        const int* __restrict__ order, float* __restrict__ out_keep) {
    int lane = threadIdx.x & 63;
    uint64_t r0 = 0, r1 = 0, r2 = 0;     // removed words: lane, lane+64, lane+128
    const int w0 = lane, w1 = lane + 64, w2 = lane + 128;
    const bool w2v = (w2 < NW);

    // prefetch chunk 0's diag word + order
    uint32_t dg_lo, dg_hi;
    {
        uint64_t dg = mask[(size_t)lane * NW + 0];
        dg_lo = (uint32_t)dg; dg_hi = (uint32_t)(dg >> 32);
    }
    int ord = order[lane];

    for (int c = 0; c < NW; c++) {
        // ---- prefetch next chunk (k_mask outputs, never mutated) ----
        uint64_t dg_n = 0; int ord_n = 0;
        if (c + 1 < NW) {
            int i2 = (c + 1) * 64 + lane;
            if (i2 < NQ) {
                dg_n  = mask[(size_t)i2 * NW + (c + 1)];
                ord_n = order[i2];
            }
        }

        // ---- removed-in word for this chunk (scalar via readlane) ----
        int cl = c & 63;
        uint32_t rlo, rhi;
        if (c < 64) {
            rlo = __builtin_amdgcn_readlane((uint32_t)r0, cl);
            rhi = __builtin_amdgcn_readlane((uint32_t)(r0 >> 32), cl);
        } else if (c < 128) {
            rlo = __builtin_amdgcn_readlane((uint32_t)r1, cl);
            rhi = __builtin_amdgcn_readlane((uint32_t)(r1 >> 32), cl);
        } else {
            rlo = __builtin_amdgcn_readlane((uint32_t)r2, cl);
            rhi = __builtin_amdgcn_readlane((uint32_t)(r2 >> 32), cl);
        }
        uint64_t cur = ((uint64_t)rhi << 32) | rlo;
        int nvalid = min(64, NQ - c * 64);
        if (nvalid < 64) cur |= (~0ull) << nvalid;   // invalid tail = suppressed

        // ---- scalar greedy resolve over alive bits ----
        uint64_t alive = ~cur;
        uint64_t kept = 0;
        while (alive) {
            int b = (int)__builtin_ctzll(alive);
            uint32_t dlo = __builtin_amdgcn_readlane(dg_lo, b);
            uint32_t dhi = __builtin_amdgcn_readlane(dg_hi, b);
            uint64_t d = ((uint64_t)dhi << 32) | dlo;   // row b's diag word (bits > b only)
            kept  |= 1ull << b;
            cur   |= d;
            alive &= ~(d | (1ull << b));
        }

        // ---- write keep for this chunk ----
        int i = c * 64 + lane;
        if (i < NQ) out_keep[ord] = ((cur >> lane) & 1ull) ? 0.f : 1.f;

        // ---- OR kept rows' suffix words into the register bitmap ----
        // two 8-row buffers issued back-to-back: 48 loads in flight, then OR
        uint64_t kmr = kept;
        uint64_t A[8][3], B[8][3];

        auto issue = [&](uint64_t (&buf)[8][3]) {
            #pragma unroll
            for (int t = 0; t < 8; t++) {
                uint64_t x0 = 0, x1 = 0, x2 = 0;
                if (kmr) {
                    int b = (int)__builtin_ctzll(kmr); kmr &= kmr - 1;
                    const unsigned long long* rp = mask + (size_t)(c * 64 + b) * NW;
                    if (w0 > c)        x0 = rp[w0];
                    if (w1 > c)        x1 = rp[w1];
                    if (w2v && w2 > c) x2 = rp[w2];
                }
                buf[t][0] = x0; buf[t][1] = x1; buf[t][2] = x2;
            }
        };
        auto consume = [&](uint64_t (&buf)[8][3]) {
            uint64_t a0 = 0, a1 = 0, a2 = 0;
            #pragma unroll
            for (int t = 0; t < 8; t++) { a0 |= buf[t][0]; a1 |= buf[t][1]; a2 |= buf[t][2]; }
            r0 |= a0; r1 |= a1; r2 |= a2;
        };

        while (kmr) {
            issue(A);
            if (!kmr) { consume(A); break; }
            issue(B);
            consume(A);
            consume(B);
        }

        dg_lo = (uint32_t)dg_n; dg_hi = (uint32_t)(dg_n >> 32); ord = ord_n;
    }
}

extern "C" void kernel_launch(void* const* d_in, const int* in_sizes, int n_in,
                              void* d_out, int out_size, void* d_ws, size_t ws_size,
                              hipStream_t stream) {
    const float* pred_logits = (const float*)d_in[0];
    const float* pred_boxes  = (const float*)d_in[1];
    const float* cls_logits  = (const float*)d_in[2];
    const int*   tsizes      = (const int*)d_in[3];

    float* out = (float*)d_out;
    float* out_scores = out;
    float* out_labels = out + 10000;
    float* out_boxes  = out + 20000;
    float* out_keep   = out + 60000;
    float* out_cls    = out + 70000;

    char* ws = (char*)d_ws;
    float* ws_scores = (float*)(ws + 0);
    int*   rank      = (int*)  (ws + 40000);
    float* boxes4    = (float*)(ws + 80000);
    float* sx1       = (float*)(ws + 240000);
    float* sy1       = (float*)(ws + 280000);
    float* sx2       = (float*)(ws + 320000);
    float* sy2       = (float*)(ws + 360000);
    float* sarea     = (float*)(ws + 400000);
    int*   order     = (int*)  (ws + 440000);
    unsigned long long* mask = (unsigned long long*)(ws + 480000);

    k_scores<<<2500, 256, 0, stream>>>(pred_logits, out_scores, out_labels, ws_scores);
    k_cls<<<1, 256, 0, stream>>>(cls_logits, out_cls);
    k_boxes<<<40, 256, 0, stream>>>(pred_boxes, tsizes, out_boxes, boxes4, rank);
    k_count<<<dim3(40, 5), 256, 0, stream>>>(ws_scores, rank);
    k_scatter<<<40, 256, 0, stream>>>(boxes4, rank, order, sx1, sy1, sx2, sy2, sarea);
    k_mask<<<dim3(157, 157), 64, 0, stream>>>(sx1, sy1, sx2, sy2, sarea, mask);
    k_scan<<<1, 64, 0, stream>>>(mask, order, out_keep);
}